// Round 8
// baseline (262.293 us; speedup 1.0000x reference)
//
#include <hip/hip_runtime.h>

// LaplacianPyramidLoss: loss = sum_l mean(|pyr(x)[l] - pyr(t)[l]|)
// Linearity: pyr(x)-pyr(t) = pyr(x-t) -> ONE pyramid of d=x-t.
// R8: direct register stencil. Evidence R5-R7: every structure with
// DEPENDENT load chains (barrier drains, register rings, shfl chains)
// pins at 1.8-3 TB/s; the 6.3 TB/s copy kernel's property is long runs
// of INDEPENDENT loads. So: each lane computes a float4 of down directly
// from 40 independent float4 loads (5 rows x 4 slots x {x,t}); L1/L2
// serve the 2.5x vertical / 2x horizontal re-reads (waves walk
// consecutive rows -> cache-hot); HBM sees each byte ~once. No LDS, no
// barriers, no shuffles. Separable 5x5 (k = g g^T exactly, g = row sums).
// Level 2 fuses the final mean(|down2|): down2 never touches HBM.

constexpr int THREADS = 256;

// LPR = lanes per down-row (64/32/16 for level 0/1/2). RG = 64/LPR rows/wave.
template <int LPR, bool FUSE, bool LAST, bool WRITE_DOWN>
__global__ __launch_bounds__(THREADS)
void lap_direct(const float* __restrict__ A,   // x (lvl0) or cur
                const float* __restrict__ Bp,  // t (lvl0) or nullptr
                const float* __restrict__ w25, // 5x5 gaussian (channel 0)
                float* __restrict__ down,      // H/2 x W/2 (if WRITE_DOWN)
                float* __restrict__ P,         // partials P[level*8+slot], [24+s]
                int H, int W, int gpi_shift, int IT, int level)
{
    const int tid  = threadIdx.x;
    const int wv   = tid >> 6, lane = tid & 63;
    const int lx   = lane & (LPR - 1);
    const int rsub = lane / LPR;
    const int Hd = H >> 1, Wd = W >> 1;
    constexpr int RG = 64 / LPR;

    // exact 1D factor: g_i = row-sum of w25 (k = g g^T since sum k = T^2)
    float g0, g1, g2, g3, g4;
    {
        float gg[5];
#pragma unroll
        for (int i = 0; i < 5; ++i) {
            float s = 0.f;
#pragma unroll
            for (int j = 0; j < 5; ++j) s += w25[i * 5 + j];
            gg[i] = s;
        }
        g0 = gg[0]; g1 = gg[1]; g2 = gg[2]; g3 = gg[3]; g4 = gg[4];
    }

    // iteration-invariant per-lane col geometry (local cols 0..15 = 8lx-4..)
    int cs0, cs1, cs2, cs3;
    {
        const int c0f = 8 * lx - 4;
        auto cl = [&](int c) { return c < 0 ? 0 : (c > W - 4 ? W - 4 : c); };
        cs0 = cl(c0f); cs1 = cl(c0f + 4); cs2 = cl(c0f + 8); cs3 = cl(c0f + 12);
    }
    const float mL = (lx == 0) ? 0.f : 1.f;        // zero cols 8lx-2,-1 at left edge
    const float mR = (lx == LPR - 1) ? 0.f : 1.f;  // zero col 8lx+8 at right edge

    const int gw = blockIdx.x * (THREADS / 64) + wv;  // global wave id
    const int gmask = (1 << gpi_shift) - 1;

    float lsum = 0.f, dsum = 0.f;
    for (int it = 0; it < IT; ++it) {
        const int g  = gw * IT + it;           // row-group index
        const int n  = g >> gpi_shift;         // image-channel (B*C fused)
        const int rg = g & gmask;
        const int r  = rg * RG + rsub;         // this lane's down row
        const size_t ib = (size_t)n * H * W;
        const int rb = 2 * r - 2;

        float h[5][4];                         // h-conv at even cols, 5 rows
        float4 p1[2], p2[2];                   // d rows 2r,2r+1 cols 8lx..8lx+7
        float gv0, gv1, gv2, gv3, gv4;         // g * row-validity (v-taps)
#pragma unroll
        for (int dy = 0; dy < 5; ++dy) {
            const int rr = rb + dy;
            const float rok = ((unsigned)rr < (unsigned)H) ? 1.f : 0.f;
            const int rc = rr < 0 ? 0 : (rr >= H ? H - 1 : rr);
            const float* rp = A + ib + (size_t)rc * W;
            float4 a0 = *(const float4*)(rp + cs0);
            float4 a1 = *(const float4*)(rp + cs1);
            float4 a2 = *(const float4*)(rp + cs2);
            float4 a3 = *(const float4*)(rp + cs3);
            if (FUSE) {
                const float* tp = Bp + ib + (size_t)rc * W;
                const float4 b0 = *(const float4*)(tp + cs0);
                const float4 b1 = *(const float4*)(tp + cs1);
                const float4 b2 = *(const float4*)(tp + cs2);
                const float4 b3 = *(const float4*)(tp + cs3);
                a0.x -= b0.x; a0.y -= b0.y; a0.z -= b0.z; a0.w -= b0.w;
                a1.x -= b1.x; a1.y -= b1.y; a1.z -= b1.z; a1.w -= b1.w;
                a2.x -= b2.x; a2.y -= b2.y; a2.z -= b2.z; a2.w -= b2.w;
                a3.x -= b3.x; a3.y -= b3.y; a3.z -= b3.z; a3.w -= b3.w;
            }
            a0.z *= mL; a0.w *= mL; a3.x *= mR;   // horizontal zero-pad
            // h at even cols 8lx+2e: window d_local[2+2e .. 6+2e]
            h[dy][0] = fmaf(g4, a1.z, fmaf(g3, a1.y, fmaf(g2, a1.x, fmaf(g1, a0.w, g0 * a0.z))));
            h[dy][1] = fmaf(g4, a2.x, fmaf(g3, a1.w, fmaf(g2, a1.z, fmaf(g1, a1.y, g0 * a1.x))));
            h[dy][2] = fmaf(g4, a2.z, fmaf(g3, a2.y, fmaf(g2, a2.x, fmaf(g1, a1.w, g0 * a1.z))));
            h[dy][3] = fmaf(g4, a3.x, fmaf(g3, a2.w, fmaf(g2, a2.z, fmaf(g1, a2.y, g0 * a2.x))));
            if (dy == 0) gv0 = g0 * rok;
            if (dy == 1) gv1 = g1 * rok;
            if (dy == 2) { gv2 = g2 * rok; p1[0] = a1; p2[0] = a2; }  // row 2r
            if (dy == 3) { gv3 = g3 * rok; p1[1] = a1; p2[1] = a2; }  // row 2r+1
            if (dy == 4) gv4 = g4 * rok;
        }
        // v-conv (row validity folded into gv)
        float4 acc;
        acc.x = fmaf(gv4, h[4][0], fmaf(gv3, h[3][0], fmaf(gv2, h[2][0], fmaf(gv1, h[1][0], gv0 * h[0][0]))));
        acc.y = fmaf(gv4, h[4][1], fmaf(gv3, h[3][1], fmaf(gv2, h[2][1], fmaf(gv1, h[1][1], gv0 * h[0][1]))));
        acc.z = fmaf(gv4, h[4][2], fmaf(gv3, h[3][2], fmaf(gv2, h[2][2], fmaf(gv1, h[1][2], gv0 * h[0][2]))));
        acc.w = fmaf(gv4, h[4][3], fmaf(gv3, h[3][3], fmaf(gv2, h[2][3], fmaf(gv1, h[1][3], gv0 * h[0][3]))));

        if (WRITE_DOWN)
            *(float4*)(down + (size_t)n * Hd * Wd + (size_t)r * Wd + 4 * lx) = acc;

        // lap = cur - up(down): rows 2r,2r+1 x cols 8lx..8lx+7
        lsum += fabsf(p1[0].x - acc.x) + fabsf(p1[0].y - acc.x)
              + fabsf(p1[0].z - acc.y) + fabsf(p1[0].w - acc.y)
              + fabsf(p2[0].x - acc.z) + fabsf(p2[0].y - acc.z)
              + fabsf(p2[0].z - acc.w) + fabsf(p2[0].w - acc.w)
              + fabsf(p1[1].x - acc.x) + fabsf(p1[1].y - acc.x)
              + fabsf(p1[1].z - acc.y) + fabsf(p1[1].w - acc.y)
              + fabsf(p2[1].x - acc.z) + fabsf(p2[1].y - acc.z)
              + fabsf(p2[1].z - acc.w) + fabsf(p2[1].w - acc.w);
        if (LAST)
            dsum += fabsf(acc.x) + fabsf(acc.y) + fabsf(acc.z) + fabsf(acc.w);
    }

    // wave reduce -> block reduce -> one spread atomic per block per level
#pragma unroll
    for (int off = 32; off > 0; off >>= 1) {
        lsum += __shfl_down(lsum, off);
        if (LAST) dsum += __shfl_down(dsum, off);
    }
    __shared__ float wsl[THREADS / 64], wsd[THREADS / 64];
    if (lane == 0) { wsl[wv] = lsum; if (LAST) wsd[wv] = dsum; }
    __syncthreads();
    if (tid == 0) {
        atomicAdd(&P[level * 8 + (blockIdx.x & 7)], wsl[0] + wsl[1] + wsl[2] + wsl[3]);
        if (LAST)
            atomicAdd(&P[24 + (blockIdx.x & 7)], wsd[0] + wsd[1] + wsd[2] + wsd[3]);
    }
}

__global__ void finalize_kernel(const float* __restrict__ P,
                                float* __restrict__ out,
                                float inv0, float inv1, float inv2, float inv3)
{
    float s0 = 0.f, s1 = 0.f, s2 = 0.f, s3 = 0.f;
#pragma unroll
    for (int i = 0; i < 8; ++i) {
        s0 += P[i]; s1 += P[8 + i]; s2 += P[16 + i]; s3 += P[24 + i];
    }
    out[0] = s0 * inv0 + s1 * inv1 + s2 * inv2 + s3 * inv3;
}

extern "C" void kernel_launch(void* const* d_in, const int* in_sizes, int n_in,
                              void* d_out, int out_size, void* d_ws, size_t ws_size,
                              hipStream_t stream)
{
    const float* x   = (const float*)d_in[0];
    const float* t   = (const float*)d_in[1];
    const float* ker = (const float*)d_in[2];  // (13,1,5,5); channels identical
    float* out = (float*)d_out;

    constexpr int B = 16, C = 13, H = 512, W = 512;
    constexpr int N = B * C;  // 208 image-channels

    // ws: [32 floats partials (pad 256B)] [down0: N*256*256] [down1: N*128*128]
    float* P     = (float*)d_ws;
    float* down0 = (float*)((char*)d_ws + 256);
    float* down1 = down0 + (size_t)N * (H / 2) * (W / 2);

    hipMemsetAsync(P, 0, 32 * sizeof(float), stream);

    dim3 blk(THREADS);
    // level 0: 512->256. LPR=64 (1 row/wave-iter), GPI=256 groups/img, IT=4.
    {
        const int Gtot = N * 256;                 // 53248 row-groups
        const int blocks = Gtot / (4 * 4);        // IT=4, 4 waves/block -> 3328
        lap_direct<64, true, false, true><<<blocks, blk, 0, stream>>>(
            x, t, ker, down0, P, H, W, 8, 4, 0);
    }
    // level 1: 256->128. LPR=32 (2 rows/iter), GPI=64, IT=2.
    {
        const int Gtot = N * 64;                  // 13312
        const int blocks = Gtot / (2 * 4);        // 1664
        lap_direct<32, false, false, true><<<blocks, blk, 0, stream>>>(
            down0, nullptr, ker, down1, P, H / 2, W / 2, 6, 2, 1);
    }
    // level 2: 128->64 (down2 in-register; fuses mean|down2|). LPR=16, GPI=16, IT=1.
    {
        const int Gtot = N * 16;                  // 3328
        const int blocks = Gtot / (1 * 4);        // 832
        lap_direct<16, false, true, false><<<blocks, blk, 0, stream>>>(
            down1, nullptr, ker, nullptr, P, H / 4, W / 4, 4, 1, 2);
    }

    const float inv0 = 1.0f / ((float)N * H * W);
    const float inv1 = 1.0f / ((float)N * (H/2) * (W/2));
    const float inv2 = 1.0f / ((float)N * (H/4) * (W/4));
    const float inv3 = 1.0f / ((float)N * (H/8) * (W/8));
    finalize_kernel<<<1, 1, 0, stream>>>(P, out, inv0, inv1, inv2, inv3);
}

// Round 9
// 243.216 us; speedup vs baseline: 1.0784x; 1.0784x over previous
//
#include <hip/hip_runtime.h>

// LaplacianPyramidLoss: loss = sum_l mean(|pyr(x)[l] - pyr(t)[l]|)
// Linearity: pyr(x)-pyr(t) = pyr(x-t) -> ONE pyramid of d=x-t.
// R9 = R6's proven pipeline (reg-prefetch next tile -> ds_write -> ONE
// lgkmcnt+s_barrier per tile -> separable h/v LDS compute) with the tile
// halved to 32x16 down-outputs: LDS 48.6 -> 25.9 KB -> 6 blocks/CU = 24
// waves = 75% occupancy (R6 ran at 30%, latency-bound at 2.9 TB/s; R1
// showed 81% occ alone isn't enough, R8 showed register-direct amplifies
// gross traffic 4x). Minimal gross traffic + high occupancy is the
// untested quadrant. Level 2 fuses mean(|down2|): down2 never hits HBM.

constexpr int THREADS = 256;
constexpr int TC = 32;              // down cols per tile
constexpr int TR = 16;              // down rows per tile
constexpr int ROWS = 2*TR + 3;      // 35 input rows (5x5 halo)
constexpr int COLS = 2*TC + 8;      // 72 float row stride (16B-aligned halo)
constexpr int SEG4 = COLS/4;        // 18 float4 per row
constexpr int TOT4 = ROWS*SEG4;     // 630 float4 per tile
constexpr int KLOAD = (TOT4 + THREADS - 1)/THREADS;   // 3 float4/thread
constexpr int HR = 11;              // h rows per wave (4 down rows + halo)
constexpr int NBLK = 1536;          // persistent: 6 blocks/CU x 256 CU

template <bool FUSE, bool LAST, bool WRITE_DOWN>
__global__ __launch_bounds__(THREADS, 6)   // 6 blocks/CU -> VGPR <= 85
void lap_level(const float* __restrict__ A,    // x (lvl0) or cur
               const float* __restrict__ Bp,   // t (lvl0) or nullptr
               const float* __restrict__ w25,  // 5x5 gaussian (channel 0)
               float* __restrict__ down,       // H/2 x W/2 (if WRITE_DOWN)
               float* __restrict__ P,          // partials P[lvl*8+s], [24+s]
               int H, int W, int ntx, int ntxy, int ntiles, int level)
{
    __shared__ __align__(16) float sdD[2][ROWS*COLS];  // 20.2 KB ping-pong
    __shared__ float sdH[4][HR*TC];                    // 5.6 KB per-wave h
    __shared__ float wsl[4], wsd[4];

    const int tid  = threadIdx.x;
    const int wv   = tid >> 6, lane = tid & 63;
    const int Hd = H >> 1, Wd = W >> 1;

    // exact 1D factor: g_i = row-sum of w25 (k = g g^T since sum k = T^2)
    float g0, g1, g2, g3, g4;
    {
        float gg[5];
#pragma unroll
        for (int i = 0; i < 5; ++i) {
            float s = 0.f;
#pragma unroll
            for (int j = 0; j < 5; ++j) s += w25[i*5 + j];
            gg[i] = s;
        }
        g0 = gg[0]; g1 = gg[1]; g2 = gg[2]; g3 = gg[3]; g4 = gg[4];
    }

    // hoisted staging coords (tid-only)
    int rr_[KLOAD], cc_[KLOAD];
#pragma unroll
    for (int k = 0; k < KLOAD; ++k) {
        const int idx = tid + k*THREADS;
        rr_[k] = idx / SEG4;
        cc_[k] = idx - rr_[k]*SEG4;
    }

    float lsum = 0.f, dsum = 0.f;
    float4 va[KLOAD], vb[KLOAD];
    int cur = blockIdx.x;
    int p = 0;

    auto issue = [&](int t) {      // all loads for tile t -> va/vb (independent)
        const int n   = t / ntxy;
        const int rem = t - n*ntxy;
        const int ty  = rem / ntx;
        const int tx  = rem - ty*ntx;
        const int gy0 = 2*ty*TR - 2;
        const int gx0 = 2*tx*TC - 4;        // 16B-aligned halo start
        const size_t ib = (size_t)n * H * W;
#pragma unroll
        for (int k = 0; k < KLOAD; ++k) {
            const int gy = gy0 + rr_[k];
            const int gx = gx0 + 4*cc_[k];  // W%4==0 -> float4 all-in/all-out
            const bool ok = (rr_[k] < ROWS) & ((unsigned)gy < (unsigned)H)
                                            & ((unsigned)gx < (unsigned)W);
            va[k] = make_float4(0.f, 0.f, 0.f, 0.f);
            if (FUSE) vb[k] = make_float4(0.f, 0.f, 0.f, 0.f);
            if (ok) {
                const size_t off = ib + (size_t)gy*W + gx;
                va[k] = *(const float4*)(A + off);
                if (FUSE) vb[k] = *(const float4*)(Bp + off);
            }
        }
    };

    if (cur < ntiles) {
        issue(cur);
        for (;;) {
            // ---- diff + write d-tile into sdD[p] (vmcnt waits land here) ----
#pragma unroll
            for (int k = 0; k < KLOAD; ++k) {
                if (rr_[k] < ROWS) {
                    float4 d = va[k];
                    if (FUSE) { d.x -= vb[k].x; d.y -= vb[k].y;
                                d.z -= vb[k].z; d.w -= vb[k].w; }
                    *(float4*)&sdD[p][rr_[k]*COLS + 4*cc_[k]] = d;
                }
            }
            // ---- issue NEXT tile's loads (fly across the barrier) ----
            const int nxt = cur + NBLK;     // gridDim.x == NBLK
            if (nxt < ntiles) issue(nxt);

            asm volatile("s_waitcnt lgkmcnt(0)" ::: "memory");
            __builtin_amdgcn_s_barrier();
            __builtin_amdgcn_sched_barrier(0);

            // ---- compute tile `cur` from sdD[p] (separable 5x5) ----
            {
                const int n   = cur / ntxy;
                const int rem = cur - n*ntxy;
                const int ty  = rem / ntx;
                const int tx  = rem - ty*ntx;
                const int oy0 = ty*TR, ox0 = tx*TC;
                const float* dd = sdD[p];
                float* hh = sdH[wv];
                const int hb = 8*wv;        // wave's input-row base (4 down rows)

                // h-pass: 11 rows x 32 even-cols, wave-private region
#pragma unroll
                for (int k = 0; k < (HR*TC + 63)/64; ++k) {
                    const int idx = lane + 64*k;
                    if (idx < HR*TC) {
                        const int hr = idx >> 5, hc = idx & 31;
                        const float* dr = &dd[(hb + hr)*COLS + 2*hc + 2];
                        float a = g0*dr[0];
                        a = fmaf(g1, dr[1], a);
                        a = fmaf(g2, dr[2], a);
                        a = fmaf(g3, dr[3], a);
                        a = fmaf(g4, dr[4], a);
                        hh[hr*TC + hc] = a;
                    }
                }
                // v-pass: 2 outputs per lane (rows rsub, rsub+2 of wave's 4)
                const int ccx = lane & 31, rsub = lane >> 5;
#pragma unroll
                for (int q = 0; q < 2; ++q) {
                    const int lr = rsub + 2*q;            // 0..3
                    float acc = g0*hh[(2*lr)*TC + ccx];
                    acc = fmaf(g1, hh[(2*lr+1)*TC + ccx], acc);
                    acc = fmaf(g2, hh[(2*lr+2)*TC + ccx], acc);
                    acc = fmaf(g3, hh[(2*lr+3)*TC + ccx], acc);
                    acc = fmaf(g4, hh[(2*lr+4)*TC + ccx], acc);
                    if (WRITE_DOWN) {
                        const int gr = oy0 + 4*wv + lr;
                        down[(size_t)n*Hd*Wd + (size_t)gr*Wd + (ox0 + ccx)] = acc;
                    }
                    // lap = cur - up(down): 2x2 input block of this down value
                    const float* cr = &dd[(hb + 2*lr + 2)*COLS + 2*ccx + 4];
                    lsum += fabsf(cr[0]    - acc) + fabsf(cr[1]      - acc)
                          + fabsf(cr[COLS] - acc) + fabsf(cr[COLS+1] - acc);
                    if (LAST) dsum += fabsf(acc);
                }
            }
            if (nxt >= ntiles) break;
            cur = nxt; p ^= 1;
        }
    }

    // ---- wave reduce -> block reduce -> one spread atomic per level ----
#pragma unroll
    for (int off = 32; off > 0; off >>= 1) {
        lsum += __shfl_down(lsum, off);
        if (LAST) dsum += __shfl_down(dsum, off);
    }
    if (lane == 0) { wsl[wv] = lsum; if (LAST) wsd[wv] = dsum; }
    __syncthreads();
    if (tid == 0) {
        atomicAdd(&P[level*8 + (blockIdx.x & 7)], wsl[0]+wsl[1]+wsl[2]+wsl[3]);
        if (LAST)
            atomicAdd(&P[24 + (blockIdx.x & 7)], wsd[0]+wsd[1]+wsd[2]+wsd[3]);
    }
}

__global__ void finalize_kernel(const float* __restrict__ P,
                                float* __restrict__ out,
                                float inv0, float inv1, float inv2, float inv3)
{
    float s0 = 0.f, s1 = 0.f, s2 = 0.f, s3 = 0.f;
#pragma unroll
    for (int i = 0; i < 8; ++i) {
        s0 += P[i]; s1 += P[8+i]; s2 += P[16+i]; s3 += P[24+i];
    }
    out[0] = s0*inv0 + s1*inv1 + s2*inv2 + s3*inv3;
}

extern "C" void kernel_launch(void* const* d_in, const int* in_sizes, int n_in,
                              void* d_out, int out_size, void* d_ws, size_t ws_size,
                              hipStream_t stream)
{
    const float* x   = (const float*)d_in[0];
    const float* t   = (const float*)d_in[1];
    const float* ker = (const float*)d_in[2];  // (13,1,5,5); channels identical
    float* out = (float*)d_out;

    constexpr int B = 16, C = 13, H = 512, W = 512;
    constexpr int N = B * C;  // 208 image-channels

    // ws: [32 floats partials (pad 256B)] [down0: N*256*256] [down1: N*128*128]
    float* P     = (float*)d_ws;
    float* down0 = (float*)((char*)d_ws + 256);
    float* down1 = down0 + (size_t)N * (H/2) * (W/2);

    hipMemsetAsync(P, 0, 32 * sizeof(float), stream);

    dim3 blk(THREADS);
    // level 0: d = x-t (fused at LDS write), 512 -> down0 256
    {
        const int ntx = (W/2)/TC, ntxy = ntx * ((H/2)/TR);   // 8 x 16 = 128
        lap_level<true, false, true><<<dim3(NBLK), blk, 0, stream>>>(
            x, t, ker, down0, P, H, W, ntx, ntxy, ntxy*N, 0);
    }
    // level 1: down0 256 -> down1 128
    {
        const int ntx = (W/4)/TC, ntxy = ntx * ((H/4)/TR);   // 4 x 8 = 32
        lap_level<false, false, true><<<dim3(NBLK), blk, 0, stream>>>(
            down0, nullptr, ker, down1, P, H/2, W/2, ntx, ntxy, ntxy*N, 1);
    }
    // level 2: down1 128 -> 64 (in-register), fuses level-3 mean(|down2|)
    {
        const int ntx = (W/8)/TC, ntxy = ntx * ((H/8)/TR);   // 2 x 4 = 8
        lap_level<false, true, false><<<dim3(NBLK), blk, 0, stream>>>(
            down1, nullptr, ker, nullptr, P, H/4, W/4, ntxy*N > 0 ? ntx : ntx, ntxy, ntxy*N, 2);
    }

    const float inv0 = 1.0f / ((float)N * H * W);
    const float inv1 = 1.0f / ((float)N * (H/2) * (W/2));
    const float inv2 = 1.0f / ((float)N * (H/4) * (W/4));
    const float inv3 = 1.0f / ((float)N * (H/8) * (W/8));
    finalize_kernel<<<1, 1, 0, stream>>>(P, out, inv0, inv1, inv2, inv3);
}